// Round 4
// baseline (623.028 us; speedup 1.0000x reference)
//
#include <hip/hip_runtime.h>

#define B_   2
#define Q_   1568
#define C_   768
#define C2_  1536
#define H_   12
#define D_   64
#define F_   8
#define S_   196
#define N_   1568
constexpr float SCALE = 0.125f;   // d^-0.5 = 64^-0.5

typedef __bf16 bf16_t;
typedef __bf16 bf16x8 __attribute__((ext_vector_type(8)));
typedef __bf16 bf16x4 __attribute__((ext_vector_type(4)));
typedef float  f32x4  __attribute__((ext_vector_type(4)));

#define AS_G __attribute__((address_space(1)))
#define AS_L __attribute__((address_space(3)))

__device__ inline void load_lds16(const void* g, void* l) {
    __builtin_amdgcn_global_load_lds((const AS_G unsigned int*)g,
                                     (AS_L unsigned int*)l, 16, 0, 0);
}

// ---------------------------------------------------------------------------
// Merged fp32 -> bf16 convert for query, memory, Wpkv (row-major bf16 copy).
// ---------------------------------------------------------------------------
#define CVT_N1 602112            // query  float4 chunks (3136*768/4)
#define CVT_N2 1204224           // + memory
#define CVT_N3 1499136           // + Wpkv (768*1536/4)
__global__ __launch_bounds__(256) void cvt3(
    const float* __restrict__ q, const float* __restrict__ mem,
    const float* __restrict__ wpkv,
    bf16_t* __restrict__ qo, bf16_t* __restrict__ mo, bf16_t* __restrict__ wo)
{
    int i = blockIdx.x * 256 + threadIdx.x;
    const float* src; bf16_t* dst; int off;
    if (i < CVT_N1)      { src = q;    dst = qo; off = i; }
    else if (i < CVT_N2) { src = mem;  dst = mo; off = i - CVT_N1; }
    else if (i < CVT_N3) { src = wpkv; dst = wo; off = i - CVT_N2; }
    else return;
    float4 v = ((const float4*)src)[off];
    bf16x4 o = { (bf16_t)v.x, (bf16_t)v.y, (bf16_t)v.z, (bf16_t)v.w };
    ((bf16x4*)dst)[off] = o;
}

// ---------------------------------------------------------------------------
// Merged W[K,N] fp32 -> Wt[N,K] bf16 for 4 weights. Grid (48, 24, 4).
// ---------------------------------------------------------------------------
__global__ __launch_bounds__(256) void transpose4(
    const float* __restrict__ W0, const float* __restrict__ W1,
    const float* __restrict__ W2, const float* __restrict__ W3,
    bf16_t* __restrict__ T0, bf16_t* __restrict__ T1,
    bf16_t* __restrict__ T2, bf16_t* __restrict__ T3)
{
    const int zi = blockIdx.z;
    const float* W = (zi == 0) ? W0 : (zi == 1) ? W1 : (zi == 2) ? W2 : W3;
    bf16_t* Wt     = (zi == 0) ? T0 : (zi == 1) ? T1 : (zi == 2) ? T2 : T3;
    const int N = (zi == 1) ? C2_ : C_;
    const int K = C_;
    const int n0 = blockIdx.x * 32;
    if (n0 >= N) return;
    __shared__ float tile[32][33];
    const int k0 = blockIdx.y * 32;
    const int t = threadIdx.x;
    const int tx = t & 31, ty = t >> 5;          // ty 0..7
#pragma unroll
    for (int i = 0; i < 4; i++)
        tile[ty + i * 8][tx] = W[(size_t)(k0 + ty + i * 8) * N + n0 + tx];
    __syncthreads();
#pragma unroll
    for (int i = 0; i < 4; i++)
        Wt[(size_t)(n0 + ty + i * 8) * K + k0 + tx] = (bf16_t)tile[tx][ty + i * 8];
}

// ---------------------------------------------------------------------------
// bf16 MFMA GEMM: C[M,N] = A[M,K] @ Bt[N,K]^T (+bias). C fp32 optional,
// Cbf bf16 optional. 128x128 tile, BK=32, 256 threads, double-buffered.
// LDS XOR swizzle (kc ^= row&3) applied on the global source of
// global_load_lds (dest linear) + matching XOR on ds_read address:
// cuts the 8-way frag-read bank conflict to ~2-4 way.
// ---------------------------------------------------------------------------
__global__ __launch_bounds__(256) void gemm_mfma(
    const bf16_t* __restrict__ A, const bf16_t* __restrict__ Bt,
    float* __restrict__ C, bf16_t* __restrict__ Cbf,
    int M, int N, int K, const float* __restrict__ bias)
{
    __shared__ bf16_t As[2][128 * 32];
    __shared__ bf16_t Bs[2][128 * 32];
    const int n0 = blockIdx.x * 128;
    const int m0 = blockIdx.y * 128;
    const int t = threadIdx.x;
    const int lane = t & 63;
    const int wv = t >> 6;                 // wave 0..3
    const int wm = wv >> 1, wn = wv & 1;   // 2x2 wave grid, 64x64 each
    const int lane15 = lane & 15, quad = lane >> 4;

    f32x4 acc[4][4];
#pragma unroll
    for (int i = 0; i < 4; i++)
#pragma unroll
        for (int j = 0; j < 4; j++) acc[i][j] = (f32x4){0.f, 0.f, 0.f, 0.f};

    // per-thread staging sources (chunk c = half*256 + t; row=c>>2, kc=c&3),
    // with source-side swizzle kc_eff = kc ^ (row & 3)
    const int row0 = t >> 2,          kc0 = (t & 3) ^ (row0 & 3);
    const int row1 = (256 + t) >> 2,  kc1 = (t & 3) ^ (row1 & 3);
    int rg0 = m0 + row0; if (rg0 >= M) rg0 = M - 1;
    int rg1 = m0 + row1; if (rg1 >= M) rg1 = M - 1;
    const bf16_t* a0 = A  + (size_t)rg0 * K + kc0 * 8;
    const bf16_t* a1 = A  + (size_t)rg1 * K + kc1 * 8;
    const bf16_t* b0 = Bt + (size_t)(n0 + row0) * K + kc0 * 8;
    const bf16_t* b1 = Bt + (size_t)(n0 + row1) * K + kc1 * 8;
    const int dst0 = (0 * 256 + wv * 64) * 16;   // + lane*16 added by HW
    const int dst1 = (1 * 256 + wv * 64) * 16;

    auto stage = [&](int buf, int k0) {
        load_lds16(a0 + k0, (char*)As[buf] + dst0);
        load_lds16(b0 + k0, (char*)Bs[buf] + dst0);
        load_lds16(a1 + k0, (char*)As[buf] + dst1);
        load_lds16(b1 + k0, (char*)Bs[buf] + dst1);
    };

    stage(0, 0);
    __syncthreads();                       // buf0 resident
    int cur = 0;
    const int posA = quad ^ (lane15 & 3);  // read-side unswizzle (chunk units)
    for (int k0 = 0; k0 < K; k0 += 32) {
        if (k0 + 32 < K) stage(cur ^ 1, k0 + 32);   // in flight during compute

        const bf16_t* Ab = As[cur];
        const bf16_t* Bb = Bs[cur];
        bf16x8 af[4], bfr[4];
#pragma unroll
        for (int i = 0; i < 4; i++) {
            af[i]  = *(const bf16x8*)(Ab + (wm * 64 + i * 16 + lane15) * 32 + posA * 8);
            bfr[i] = *(const bf16x8*)(Bb + (wn * 64 + i * 16 + lane15) * 32 + posA * 8);
        }
#pragma unroll
        for (int i = 0; i < 4; i++)
#pragma unroll
            for (int j = 0; j < 4; j++)
                acc[i][j] = __builtin_amdgcn_mfma_f32_16x16x32_bf16(af[i], bfr[j], acc[i][j], 0, 0, 0);

        __syncthreads();                   // drains next-tile stage
        cur ^= 1;
    }

#pragma unroll
    for (int i = 0; i < 4; i++) {
#pragma unroll
        for (int j = 0; j < 4; j++) {
            int col = n0 + wn * 64 + j * 16 + lane15;
            float bb = bias ? bias[col] : 0.f;
#pragma unroll
            for (int r = 0; r < 4; r++) {
                int row = m0 + wm * 64 + i * 16 + quad * 4 + r;
                if (row < M) {
                    float v = acc[i][j][r] + bb;
                    if (C)   C[(size_t)row * N + col] = v;
                    if (Cbf) Cbf[(size_t)row * N + col] = (bf16_t)v;
                }
            }
        }
    }
}

// ---------------------------------------------------------------------------
// Per-head G GEMM: G[bq, h, c1] = sum_j q2[bq, h*64+j] * Wpkv[c1, h*64+j]
// (j over the head's 64 dims; Wpkv row-major bf16, k-half cols 0..767 used
//  via col offset h*64 < 768). M=3136, N=768, K=64 single-stage.
// Grid (6, 25, 12), 256 threads. LDS swizzle kc ^= row&7 (stride 128B).
// ---------------------------------------------------------------------------
__global__ __launch_bounds__(256) void gemm_g(
    const bf16_t* __restrict__ q2b, const bf16_t* __restrict__ wkvb,
    bf16_t* __restrict__ G, int M)
{
    __shared__ bf16_t As[128 * 64];
    __shared__ bf16_t Bs[128 * 64];
    const int n0 = blockIdx.x * 128;
    const int m0 = blockIdx.y * 128;
    const int h  = blockIdx.z;
    const int t = threadIdx.x;
    const int lane = t & 63, wv = t >> 6;
    const int wm = wv >> 1, wn = wv & 1;
    const int lane15 = lane & 15, quad = lane >> 4;

    // stage A,B: 1024 chunks each; row = c>>3, kc = (c&7) ^ (row&7)
#pragma unroll
    for (int i = 0; i < 4; i++) {
        int c = i * 256 + t;
        int row = c >> 3, kc = (c & 7) ^ (row & 7);
        int rg = m0 + row; if (rg >= M) rg = M - 1;
        load_lds16(q2b + (size_t)rg * C_ + h * 64 + kc * 8,
                   (char*)As + (i * 256 + wv * 64) * 16);
        load_lds16(wkvb + (size_t)(n0 + row) * C2_ + h * 64 + kc * 8,
                   (char*)Bs + (i * 256 + wv * 64) * 16);
    }
    __syncthreads();

    f32x4 acc[4][4];
#pragma unroll
    for (int i = 0; i < 4; i++)
#pragma unroll
        for (int j = 0; j < 4; j++) acc[i][j] = (f32x4){0.f, 0.f, 0.f, 0.f};

    bf16x8 af[4][2], bfr[4][2];
#pragma unroll
    for (int i = 0; i < 4; i++)
#pragma unroll
        for (int kk = 0; kk < 2; kk++) {
            int rowa = wm * 64 + i * 16 + lane15;
            int rowb = wn * 64 + i * 16 + lane15;
            int pos = (kk * 4 + quad) ^ (lane15 & 7);
            af[i][kk]  = *(const bf16x8*)(As + rowa * 64 + pos * 8);
            bfr[i][kk] = *(const bf16x8*)(Bs + rowb * 64 + pos * 8);
        }
#pragma unroll
    for (int i = 0; i < 4; i++)
#pragma unroll
        for (int j = 0; j < 4; j++)
#pragma unroll
            for (int kk = 0; kk < 2; kk++)
                acc[i][j] = __builtin_amdgcn_mfma_f32_16x16x32_bf16(af[i][kk], bfr[j][kk], acc[i][j], 0, 0, 0);

#pragma unroll
    for (int i = 0; i < 4; i++)
#pragma unroll
        for (int j = 0; j < 4; j++) {
            int col = n0 + wn * 64 + j * 16 + lane15;
#pragma unroll
            for (int r = 0; r < 4; r++) {
                int row = m0 + wm * 64 + i * 16 + quad * 4 + r;
                if (row < M)
                    G[(size_t)row * (H_ * C_) + h * C_ + col] = (bf16_t)acc[i][j][r];
            }
        }
}

// ---------------------------------------------------------------------------
// logits2[bq, h, f] = SCALE * sum_c1 x[bq,f,c1] * G[bq,h,c1]. Grid 3136.
// ---------------------------------------------------------------------------
__global__ __launch_bounds__(256) void l2_kernel(
    const bf16_t* __restrict__ x, const bf16_t* __restrict__ G,
    float* __restrict__ l2out)
{
    __shared__ bf16_t xs[F_ * C_];    // 12 KB
    __shared__ bf16_t gs[H_ * C_];    // 18 KB
    const int bq = blockIdx.x;
    const int t = threadIdx.x;
    const bf16x8* xsrc = (const bf16x8*)(x + (size_t)bq * F_ * C_);
    for (int e = t; e < F_ * C_ / 8; e += 256) ((bf16x8*)xs)[e] = xsrc[e];
    const bf16x8* gsrc = (const bf16x8*)(G + (size_t)bq * H_ * C_);
    for (int e = t; e < H_ * C_ / 8; e += 256) ((bf16x8*)gs)[e] = gsrc[e];
    __syncthreads();
    if (t < 96) {                     // t = h*8 + f
        int h = t >> 3, f = t & 7;
        float acc = 0.f;
        for (int c = 0; c < C_; c += 8) {
            bf16x8 xv = *(const bf16x8*)(xs + f * C_ + c);
            bf16x8 gv = *(const bf16x8*)(gs + h * C_ + c);
#pragma unroll
            for (int j = 0; j < 8; j++) acc += (float)xv[j] * (float)gv[j];
        }
        l2out[(size_t)bq * 96 + t] = SCALE * acc;
    }
}

// ---------------------------------------------------------------------------
// Fused stage-1 attention with T14 async-stage split:
//   issue V global loads -> regs (entry), QK^T -> out1, softmax,
//   THEN write V regs->LDS + P->LDS, single barrier, PV, fused xsum.
// Grid (F=8, 14, 24), 448 threads (7 waves). LDS 81,664 B (1 block/CU).
// ---------------------------------------------------------------------------
__global__ __launch_bounds__(448, 4) void attn1_fused(
    const bf16_t* __restrict__ qb, const bf16_t* __restrict__ kvb,
    float* __restrict__ out1, bf16_t* __restrict__ x, float* __restrict__ xsum)
{
    __shared__ bf16_t Vt[64 * 232];          // V transposed: [d][s], s padded to 224
    __shared__ bf16_t Ps[7 * 16 * 232];      // per-wave P tile [16 q][s padded]
    const int f = blockIdx.x, qt = blockIdx.y, z = blockIdx.z;
    const int b = z / H_, h = z - b * H_;
    const int t = threadIdx.x;
    const int lane = t & 63, w = t >> 6;     // wave 0..6
    const int lane15 = lane & 15, quad = lane >> 4;

    const size_t kvBase = ((size_t)b * N_ + (size_t)f * S_) * C2_;

    // ---- (1) issue V loads to registers (consumed after softmax) ----
    bf16x8 vreg[4];
#pragma unroll
    for (int i = 0; i < 4; i++) {
        int e = t + 448 * i;                 // 0..1791; valid < 1568
        int dg = e / S_, s = e - dg * S_;
        if (e >= 8 * S_) { dg = 0; s = 0; }  // safe dup address
        vreg[i] = *(const bf16x8*)(kvb + kvBase + (size_t)s * C2_ + C_ + h * D_ + dg * 8);
    }

    // ---- (2) Q A-frags ----
    const int qrow = qt * 112 + w * 16 + lane15;
    const bf16_t* qp = qb + ((size_t)b * Q_ + qrow) * C_ + h * D_ + quad * 8;
    bf16x8 qa0 = *(const bf16x8*)(qp);
    bf16x8 qa1 = *(const bf16x8*)(qp + 32);

    // ---- (3) zero V pad cols s in [196,224) + own-wave P pad [208,224) ----
#pragma unroll
    for (int i = 0; i < 4; i++) {
        int e = t + 448 * i;                 // 0..1791 = 64*28
        if (e < 64 * 28) {
            int dd = e / 28;
            int s  = S_ + (e - dd * 28);
            Vt[dd * 232 + s] = (bf16_t)0.f;
        }
    }
    bf16_t* Pw = Ps + w * (16 * 232);
    {
        int prow = lane >> 2, c0 = 208 + (lane & 3) * 4;
        *(bf16x4*)(Pw + prow * 232 + c0) =
            (bf16x4){(bf16_t)0.f, (bf16_t)0.f, (bf16_t)0.f, (bf16_t)0.f};
    }

    // ---- (4) QK^T: 13 n-tiles of 16 keys, K frags from global (L2-hot) ----
    f32x4 acc[13];
#pragma unroll
    for (int n = 0; n < 13; n++) acc[n] = (f32x4){0.f, 0.f, 0.f, 0.f};
#pragma unroll
    for (int n = 0; n < 13; n++) {
        int srow = n * 16 + lane15; if (srow > S_ - 1) srow = S_ - 1;  // clamp pad rows
        const bf16_t* kp = kvb + kvBase + (size_t)srow * C2_ + h * D_ + quad * 8;
        bf16x8 kb0 = *(const bf16x8*)(kp);
        bf16x8 kb1 = *(const bf16x8*)(kp + 32);
        acc[n] = __builtin_amdgcn_mfma_f32_16x16x32_bf16(qa0, kb0, acc[n], 0, 0, 0);
        acc[n] = __builtin_amdgcn_mfma_f32_16x16x32_bf16(qa1, kb1, acc[n], 0, 0, 0);
    }

    // acc[n][r] = S[q = w*16 + quad*4 + r][s = n*16 + lane15]
    // ---- scale, write logits (output 1), mask pad ----
    const size_t o1base = ((size_t)z * Q_ + qt * 112 + w * 16 + quad * 4) * N_ + (size_t)f * S_;
#pragma unroll
    for (int n = 0; n < 13; n++) {
        int s = n * 16 + lane15;
        bool valid = s < S_;
#pragma unroll
        for (int r = 0; r < 4; r++) {
            float v = SCALE * acc[n][r];
            if (valid) out1[o1base + (size_t)r * N_ + s] = v;
            acc[n][r] = valid ? v : -3e38f;
        }
    }

    // ---- softmax over s: reduce across lane15 (16-lane groups) ----
    float m[4], inv[4];
#pragma unroll
    for (int r = 0; r < 4; r++) {
        float mm = acc[0][r];
#pragma unroll
        for (int n = 1; n < 13; n++) mm = fmaxf(mm, acc[n][r]);
        mm = fmaxf(mm, __shfl_xor(mm, 1));
        mm = fmaxf(mm, __shfl_xor(mm, 2));
        mm = fmaxf(mm, __shfl_xor(mm, 4));
        mm = fmaxf(mm, __shfl_xor(mm, 8));
        m[r] = mm;
    }
#pragma unroll
    for (int r = 0; r < 4; r++) {
        float ss = 0.f;
#pragma unroll
        for (int n = 0; n < 13; n++) {
            float e = __expf(acc[n][r] - m[r]);   // masked -> exp(-huge) = 0
            acc[n][r] = e;
            ss += e;
        }
        ss += __shfl_xor(ss, 1);
        ss += __shfl_xor(ss, 2);
        ss += __shfl_xor(ss, 4);
        ss += __shfl_xor(ss, 8);
        inv[r] = 1.f / ss;
    }

    // ---- (5) late V write: regs -> Vt (HBM latency hidden under QK^T) ----
#pragma unroll
    for (int i = 0; i < 4; i++) {
        int e = t + 448 * i;
        if (e < 8 * S_) {
            int dg = e / S_, s = e - dg * S_;
#pragma unroll
            for (int j = 0; j < 8; j++)
                Vt[(dg * 8 + j) * 232 + s] = vreg[i][j];
        }
    }

    // ---- (6) write normalized P (bf16) to own-wave LDS tile ----
#pragma unroll
    for (int n = 0; n < 13; n++)
#pragma unroll
        for (int r = 0; r < 4; r++)
            Pw[(quad * 4 + r) * 232 + n * 16 + lane15] = (bf16_t)(acc[n][r] * inv[r]);

    __syncthreads();                         // single barrier: Vt + Ps ready

    // ---- (7) PV: x[16 q][64 d] = P[16][224] @ V[224][64], 7 k-chunks ----
    bf16x8 pa[7];
#pragma unroll
    for (int ks = 0; ks < 7; ks++)
        pa[ks] = *(const bf16x8*)(Pw + lane15 * 232 + ks * 32 + quad * 8);

    f32x4 o[4];
#pragma unroll
    for (int nt = 0; nt < 4; nt++) o[nt] = (f32x4){0.f, 0.f, 0.f, 0.f};
#pragma unroll
    for (int nt = 0; nt < 4; nt++)
#pragma unroll
        for (int ks = 0; ks < 7; ks++) {
            bf16x8 vb = *(const bf16x8*)(Vt + (nt * 16 + lane15) * 232 + ks * 32 + quad * 8);
            o[nt] = __builtin_amdgcn_mfma_f32_16x16x32_bf16(pa[ks], vb, o[nt], 0, 0, 0);
        }

    // o[nt][r]: row q = w*16 + quad*4 + r, col d = nt*16 + lane15
    const int qb2 = qt * 112 + w * 16 + quad * 4;
#pragma unroll
    for (int nt = 0; nt < 4; nt++)
#pragma unroll
        for (int r = 0; r < 4; r++)
            x[(((size_t)(b * Q_ + qb2 + r)) * F_ + f) * C_ + h * D_ + nt * 16 + lane15] =
                (bf16_t)o[nt][r];

    // ---- fused xsum: block-level sum over its 112 q rows, then 64 atomics ----
    float part[4];
#pragma unroll
    for (int nt = 0; nt < 4; nt++)
        part[nt] = o[nt][0] + o[nt][1] + o[nt][2] + o[nt][3];
    __syncthreads();                       // Vt/Ps dead in all waves
    float* red = (float*)Vt;               // reuse LDS
    if (t < 64) red[t] = 0.f;
    __syncthreads();
#pragma unroll
    for (int nt = 0; nt < 4; nt++)
        atomicAdd(&red[nt * 16 + lane15], part[nt]);
    __syncthreads();
    if (t < 64)
        atomicAdd(&xsum[((size_t)(b * F_ + f)) * C_ + h * D_ + t], red[t]);
}

// ---------------------------------------------------------------------------
// vsum[b,f,c2] = sum_c xsum[b,f,c] * Wpkv[c, 768+c2]. Grid (16, 3).
// ---------------------------------------------------------------------------
__global__ __launch_bounds__(256) void vsum_kernel(
    const float* __restrict__ xsum, const float* __restrict__ Wpkv,
    float* __restrict__ vsum)
{
    __shared__ float xs[C_];
    const int bf = blockIdx.x;
    const int t = threadIdx.x;
    for (int i = 0; i < 3; i++) xs[t + 256 * i] = xsum[(size_t)bf * C_ + t + 256 * i];
    __syncthreads();
    const int c2 = blockIdx.y * 256 + t;
    float acc = 0.f;
#pragma unroll 8
    for (int c = 0; c < C_; c++) acc += xs[c] * Wpkv[(size_t)c * C2_ + C_ + c2];
    vsum[(size_t)bf * C_ + c2] = acc;
}

// ---------------------------------------------------------------------------
// Stage-2: softmax over f (logits from l2_kernel), then
// qout[b,q,c] = sum_f p2 * vsum. Out bf16. Grid 3136 blocks.
// ---------------------------------------------------------------------------
__global__ __launch_bounds__(256) void attn2_qout(
    const float* __restrict__ logits2, const float* __restrict__ vsum,
    bf16_t* __restrict__ qout)
{
    __shared__ float p2s[96];
    const int bq = blockIdx.x;
    const int t = threadIdx.x;

    if (t < 96) {                           // t = h*8 + f
        float l = logits2[(size_t)bq * 96 + t];
        float mm = l;
        mm = fmaxf(mm, __shfl_xor(mm, 1));
        mm = fmaxf(mm, __shfl_xor(mm, 2));
        mm = fmaxf(mm, __shfl_xor(mm, 4));  // 8-lane group (same h) max
        float e = __expf(l - mm);
        float ss = e;
        ss += __shfl_xor(ss, 1);
        ss += __shfl_xor(ss, 2);
        ss += __shfl_xor(ss, 4);
        p2s[t] = e / ss;
    }
    __syncthreads();

    const int b = bq / Q_;
    for (int i = 0; i < 3; i++) {
        int c = t + 256 * i;
        int h = c >> 6;
        float acc = 0.f;
#pragma unroll
        for (int fr = 0; fr < F_; fr++)
            acc += p2s[h * 8 + fr] * vsum[((size_t)(b * F_ + fr)) * C_ + c];
        qout[(size_t)bq * C_ + c] = (bf16_t)acc;
    }
}

// ---------------------------------------------------------------------------
extern "C" void kernel_launch(void* const* d_in, const int* in_sizes, int n_in,
                              void* d_out, int out_size, void* d_ws, size_t ws_size,
                              hipStream_t stream) {
    const float* query  = (const float*)d_in[0];
    const float* memory = (const float*)d_in[1];
    const float* Wq     = (const float*)d_in[2];
    const float* Wkv    = (const float*)d_in[3];
    const float* Wpq    = (const float*)d_in[4];
    const float* Wpkv   = (const float*)d_in[5];
    const float* Wproj  = (const float*)d_in[6];
    const float* bproj  = (const float*)d_in[7];

    float* out0 = (float*)d_out;                              // [B,Q,C]
    float* out1 = (float*)d_out + (size_t)B_ * Q_ * C_;       // [B*H,Q,F,S]

    char* w = (char*)d_ws;                       // byte offsets, all 16B aligned
    bf16_t* kv_bf = (bf16_t*)(w + 0);            //   9,633,792  [B*N, 2C]
    bf16_t* q_bf  = (bf16_t*)(w + 9633792);      //   4,816,896  [B*Q, C]
    bf16_t* q2b   = (bf16_t*)(w + 14450688);     //   4,816,896  [B*Q, C]
    bf16_t* qry_b = (bf16_t*)(w + 19267584);     //   4,816,896
    bf16_t* mem_b = (bf16_t*)(w + 24084480);     //   4,816,896
    bf16_t* qo_bf = (bf16_t*)(w + 28901376);     //   4,816,896
    bf16_t* x_bf  = (bf16_t*)(w + 33718272);     //  38,535,168  [B*Q*F, C]
    bf16_t* G_bf  = (bf16_t*)(w + 72253440);     //  57,802,752  [B*Q, H, C]
    float*  lgt2  = (float*) (w + 130056192);    //   1,204,224  [B*Q, H, F]
    bf16_t* Wqt   = (bf16_t*)(w + 131260416);    //   1,179,648
    bf16_t* Wkvt  = (bf16_t*)(w + 132440064);    //   2,359,296
    bf16_t* Wpqt  = (bf16_t*)(w + 134799360);    //   1,179,648
    bf16_t* Wprjt = (bf16_t*)(w + 135979008);    //   1,179,648
    bf16_t* Wpkvb = (bf16_t*)(w + 137158656);    //   2,359,296  [C, 2C] row-major
    float*  xsum  = (float*) (w + 139517952);    //      49,152
    float*  vsum  = (float*) (w + 139567104);    //      49,152

    const int MQ = B_ * Q_;        // 3136
    const int MN = B_ * N_;        // 3136

    // merged input conversions (query, memory, Wpkv->bf16 row-major)
    cvt3<<<5856, 256, 0, stream>>>(query, memory, Wpkv, qry_b, mem_b, Wpkvb);
    // merged weight transposes (Wq, Wkv, Wpq, Wproj)
    transpose4<<<dim3(48, 24, 4), 256, 0, stream>>>(Wq, Wkv, Wpq, Wproj,
                                                    Wqt, Wkvt, Wpqt, Wprjt);

    // q = query @ Wq (bf16)
    gemm_mfma<<<dim3(6, 25), 256, 0, stream>>>(qry_b, Wqt, nullptr, q_bf, MQ, C_, C_, nullptr);
    // kv = memory @ Wkv (bf16)
    gemm_mfma<<<dim3(12, 25), 256, 0, stream>>>(mem_b, Wkvt, nullptr, kv_bf, MN, C2_, C_, nullptr);
    // q2 = q @ Wpq (bf16)
    gemm_mfma<<<dim3(6, 25), 256, 0, stream>>>(q_bf, Wpqt, nullptr, q2b, MQ, C_, C_, nullptr);
    // fused stage-1: logits (output 1) + softmax + PV -> x (bf16) + xsum
    hipMemsetAsync(xsum, 0, (size_t)B_ * F_ * C_ * sizeof(float), stream);
    attn1_fused<<<dim3(F_, 14, B_ * H_), 448, 0, stream>>>(q_bf, kv_bf, out1, x_bf, xsum);
    // G[bq,h,:] = Wpkv_k-head-slice @ q2-head-slice  (replaces 29.6GF k2 GEMM)
    gemm_g<<<dim3(6, 25, H_), 256, 0, stream>>>(q2b, Wpkvb, G_bf, MQ);
    // logits2 = SCALE * x . G  (x read exactly once)
    l2_kernel<<<MQ, 256, 0, stream>>>(x_bf, G_bf, lgt2);
    // vsum = xsum @ Wpkv[:, 768:]
    vsum_kernel<<<dim3(16, 3), 256, 0, stream>>>(xsum, Wpkv, vsum);
    // stage-2 attention -> qout (bf16, pre-projection)
    attn2_qout<<<MQ, 256, 0, stream>>>(lgt2, vsum, qo_bf);
    // out0 = qout @ Wproj + bproj
    gemm_mfma<<<dim3(6, 25), 256, 0, stream>>>(qo_bf, Wprjt, out0, nullptr, MQ, C_, C_, bproj);
}

// Round 6
// 572.341 us; speedup vs baseline: 1.0886x; 1.0886x over previous
//
#include <hip/hip_runtime.h>

#define B_   2
#define Q_   1568
#define C_   768
#define C2_  1536
#define H_   12
#define D_   64
#define F_   8
#define S_   196
#define N_   1568
constexpr float SCALE = 0.125f;   // d^-0.5 = 64^-0.5

typedef __bf16 bf16_t;
typedef __bf16 bf16x8 __attribute__((ext_vector_type(8)));
typedef __bf16 bf16x4 __attribute__((ext_vector_type(4)));
typedef float  f32x4  __attribute__((ext_vector_type(4)));

#define AS_G __attribute__((address_space(1)))
#define AS_L __attribute__((address_space(3)))

__device__ inline void load_lds16(const void* g, void* l) {
    __builtin_amdgcn_global_load_lds((const AS_G unsigned int*)g,
                                     (AS_L unsigned int*)l, 16, 0, 0);
}

// ---------------------------------------------------------------------------
// Merged fp32 -> bf16 convert for query, memory, Wpkv (row-major bf16 copy).
// ---------------------------------------------------------------------------
#define CVT_N1 602112            // query  float4 chunks (3136*768/4)
#define CVT_N2 1204224           // + memory
#define CVT_N3 1499136           // + Wpkv (768*1536/4)
__global__ __launch_bounds__(256) void cvt3(
    const float* __restrict__ q, const float* __restrict__ mem,
    const float* __restrict__ wpkv,
    bf16_t* __restrict__ qo, bf16_t* __restrict__ mo, bf16_t* __restrict__ wo)
{
    int i = blockIdx.x * 256 + threadIdx.x;
    const float* src; bf16_t* dst; int off;
    if (i < CVT_N1)      { src = q;    dst = qo; off = i; }
    else if (i < CVT_N2) { src = mem;  dst = mo; off = i - CVT_N1; }
    else if (i < CVT_N3) { src = wpkv; dst = wo; off = i - CVT_N2; }
    else return;
    float4 v = ((const float4*)src)[off];
    bf16x4 o = { (bf16_t)v.x, (bf16_t)v.y, (bf16_t)v.z, (bf16_t)v.w };
    ((bf16x4*)dst)[off] = o;
}

// ---------------------------------------------------------------------------
// Merged W[K,N] fp32 -> Wt[N,K] bf16 for 4 weights. Grid (48, 24, 4).
// ---------------------------------------------------------------------------
__global__ __launch_bounds__(256) void transpose4(
    const float* __restrict__ W0, const float* __restrict__ W1,
    const float* __restrict__ W2, const float* __restrict__ W3,
    bf16_t* __restrict__ T0, bf16_t* __restrict__ T1,
    bf16_t* __restrict__ T2, bf16_t* __restrict__ T3)
{
    const int zi = blockIdx.z;
    const float* W = (zi == 0) ? W0 : (zi == 1) ? W1 : (zi == 2) ? W2 : W3;
    bf16_t* Wt     = (zi == 0) ? T0 : (zi == 1) ? T1 : (zi == 2) ? T2 : T3;
    const int N = (zi == 1) ? C2_ : C_;
    const int K = C_;
    const int n0 = blockIdx.x * 32;
    if (n0 >= N) return;
    __shared__ float tile[32][33];
    const int k0 = blockIdx.y * 32;
    const int t = threadIdx.x;
    const int tx = t & 31, ty = t >> 5;          // ty 0..7
#pragma unroll
    for (int i = 0; i < 4; i++)
        tile[ty + i * 8][tx] = W[(size_t)(k0 + ty + i * 8) * N + n0 + tx];
    __syncthreads();
#pragma unroll
    for (int i = 0; i < 4; i++)
        Wt[(size_t)(n0 + ty + i * 8) * K + k0 + tx] = (bf16_t)tile[tx][ty + i * 8];
}

// ---------------------------------------------------------------------------
// bf16 MFMA GEMM body: C[M,N] = A[M,K] @ Bt[N,K]^T (+bias). 128x128 tile,
// BK=32, 256 threads, double-buffered, source-side XOR swizzle. LDS buffers
// are passed in by the wrapper kernels (avoids duplicate __shared__ when two
// call sites are inlined into one kernel).
// ---------------------------------------------------------------------------
__device__ inline void gemm_body(
    const bf16_t* __restrict__ A, const bf16_t* __restrict__ Bt,
    float* __restrict__ C, bf16_t* __restrict__ Cbf,
    int M, int N, int K, const float* __restrict__ bias,
    int bx, int by, bf16_t* As, bf16_t* Bs)      // As,Bs: 2*128*32 each
{
    const int n0 = bx * 128;
    const int m0 = by * 128;
    const int t = threadIdx.x;
    const int lane = t & 63;
    const int wv = t >> 6;                 // wave 0..3
    const int wm = wv >> 1, wn = wv & 1;   // 2x2 wave grid, 64x64 each
    const int lane15 = lane & 15, quad = lane >> 4;

    f32x4 acc[4][4];
#pragma unroll
    for (int i = 0; i < 4; i++)
#pragma unroll
        for (int j = 0; j < 4; j++) acc[i][j] = (f32x4){0.f, 0.f, 0.f, 0.f};

    // per-thread staging sources (chunk c = half*256 + t; row=c>>2, kc=c&3),
    // with source-side swizzle kc_eff = kc ^ (row & 3)
    const int row0 = t >> 2,          kc0 = (t & 3) ^ (row0 & 3);
    const int row1 = (256 + t) >> 2,  kc1 = (t & 3) ^ (row1 & 3);
    int rg0 = m0 + row0; if (rg0 >= M) rg0 = M - 1;
    int rg1 = m0 + row1; if (rg1 >= M) rg1 = M - 1;
    const bf16_t* a0 = A  + (size_t)rg0 * K + kc0 * 8;
    const bf16_t* a1 = A  + (size_t)rg1 * K + kc1 * 8;
    const bf16_t* b0 = Bt + (size_t)(n0 + row0) * K + kc0 * 8;
    const bf16_t* b1 = Bt + (size_t)(n0 + row1) * K + kc1 * 8;
    const int dst0 = (0 * 256 + wv * 64) * 16;   // + lane*16 added by HW
    const int dst1 = (1 * 256 + wv * 64) * 16;

    auto stage = [&](int buf, int k0) {
        load_lds16(a0 + k0, (char*)(As + buf * 128 * 32) + dst0);
        load_lds16(b0 + k0, (char*)(Bs + buf * 128 * 32) + dst0);
        load_lds16(a1 + k0, (char*)(As + buf * 128 * 32) + dst1);
        load_lds16(b1 + k0, (char*)(Bs + buf * 128 * 32) + dst1);
    };

    stage(0, 0);
    __syncthreads();                       // buf0 resident
    int cur = 0;
    const int posA = quad ^ (lane15 & 3);  // read-side unswizzle (chunk units)
    for (int k0 = 0; k0 < K; k0 += 32) {
        if (k0 + 32 < K) stage(cur ^ 1, k0 + 32);   // in flight during compute

        const bf16_t* Ab = As + cur * 128 * 32;
        const bf16_t* Bb = Bs + cur * 128 * 32;
        bf16x8 af[4], bfr[4];
#pragma unroll
        for (int i = 0; i < 4; i++) {
            af[i]  = *(const bf16x8*)(Ab + (wm * 64 + i * 16 + lane15) * 32 + posA * 8);
            bfr[i] = *(const bf16x8*)(Bb + (wn * 64 + i * 16 + lane15) * 32 + posA * 8);
        }
#pragma unroll
        for (int i = 0; i < 4; i++)
#pragma unroll
            for (int j = 0; j < 4; j++)
                acc[i][j] = __builtin_amdgcn_mfma_f32_16x16x32_bf16(af[i], bfr[j], acc[i][j], 0, 0, 0);

        __syncthreads();                   // drains next-tile stage
        cur ^= 1;
    }

#pragma unroll
    for (int i = 0; i < 4; i++) {
#pragma unroll
        for (int j = 0; j < 4; j++) {
            int col = n0 + wn * 64 + j * 16 + lane15;
            float bb = bias ? bias[col] : 0.f;
#pragma unroll
            for (int r = 0; r < 4; r++) {
                int row = m0 + wm * 64 + i * 16 + quad * 4 + r;
                if (row < M) {
                    float v = acc[i][j][r] + bb;
                    if (C)   C[(size_t)row * N + col] = v;
                    if (Cbf) Cbf[(size_t)row * N + col] = (bf16_t)v;
                }
            }
        }
    }
}

__global__ __launch_bounds__(256) void gemm_mfma(
    const bf16_t* __restrict__ A, const bf16_t* __restrict__ Bt,
    float* __restrict__ C, bf16_t* __restrict__ Cbf,
    int M, int N, int K, const float* __restrict__ bias)
{
    __shared__ bf16_t As[2 * 128 * 32];
    __shared__ bf16_t Bs[2 * 128 * 32];
    gemm_body(A, Bt, C, Cbf, M, N, K, bias, blockIdx.x, blockIdx.y, As, Bs);
}

// Merged q-GEMM (6 x-blocks) + kv-GEMM (12 x-blocks): grid (18, 25).
__global__ __launch_bounds__(256) void gemm_qkv(
    const bf16_t* __restrict__ qry, const bf16_t* __restrict__ Wqt,
    bf16_t* __restrict__ qo,
    const bf16_t* __restrict__ mem, const bf16_t* __restrict__ Wkvt,
    bf16_t* __restrict__ kvo)
{
    __shared__ bf16_t As[2 * 128 * 32];
    __shared__ bf16_t Bs[2 * 128 * 32];
    if (blockIdx.x < 6)
        gemm_body(qry, Wqt, nullptr, qo,  B_ * Q_, C_,  C_, nullptr, blockIdx.x,     blockIdx.y, As, Bs);
    else
        gemm_body(mem, Wkvt, nullptr, kvo, B_ * N_, C2_, C_, nullptr, blockIdx.x - 6, blockIdx.y, As, Bs);
}

// ---------------------------------------------------------------------------
// Per-head G GEMM: G[bq, h, c1] = sum_j q2[bq, h*64+j] * Wpkv[c1, h*64+j].
// Grid (6, 25, 12), 256 threads, K=64 single-stage, swizzled staging.
// ---------------------------------------------------------------------------
__global__ __launch_bounds__(256) void gemm_g(
    const bf16_t* __restrict__ q2b, const bf16_t* __restrict__ wkvb,
    bf16_t* __restrict__ G, int M)
{
    __shared__ bf16_t As[128 * 64];
    __shared__ bf16_t Bs[128 * 64];
    const int n0 = blockIdx.x * 128;
    const int m0 = blockIdx.y * 128;
    const int h  = blockIdx.z;
    const int t = threadIdx.x;
    const int lane = t & 63, wv = t >> 6;
    const int wm = wv >> 1, wn = wv & 1;
    const int lane15 = lane & 15, quad = lane >> 4;

#pragma unroll
    for (int i = 0; i < 4; i++) {
        int c = i * 256 + t;
        int row = c >> 3, kc = (c & 7) ^ (row & 7);
        int rg = m0 + row; if (rg >= M) rg = M - 1;
        load_lds16(q2b + (size_t)rg * C_ + h * 64 + kc * 8,
                   (char*)As + (i * 256 + wv * 64) * 16);
        load_lds16(wkvb + (size_t)(n0 + row) * C2_ + h * 64 + kc * 8,
                   (char*)Bs + (i * 256 + wv * 64) * 16);
    }
    __syncthreads();

    f32x4 acc[4][4];
#pragma unroll
    for (int i = 0; i < 4; i++)
#pragma unroll
        for (int j = 0; j < 4; j++) acc[i][j] = (f32x4){0.f, 0.f, 0.f, 0.f};

    bf16x8 af[4][2], bfr[4][2];
#pragma unroll
    for (int i = 0; i < 4; i++)
#pragma unroll
        for (int kk = 0; kk < 2; kk++) {
            int rowa = wm * 64 + i * 16 + lane15;
            int rowb = wn * 64 + i * 16 + lane15;
            int pos = (kk * 4 + quad) ^ (lane15 & 7);
            af[i][kk]  = *(const bf16x8*)(As + rowa * 64 + pos * 8);
            bfr[i][kk] = *(const bf16x8*)(Bs + rowb * 64 + pos * 8);
        }
#pragma unroll
    for (int i = 0; i < 4; i++)
#pragma unroll
        for (int j = 0; j < 4; j++)
#pragma unroll
            for (int kk = 0; kk < 2; kk++)
                acc[i][j] = __builtin_amdgcn_mfma_f32_16x16x32_bf16(af[i][kk], bfr[j][kk], acc[i][j], 0, 0, 0);

#pragma unroll
    for (int i = 0; i < 4; i++)
#pragma unroll
        for (int j = 0; j < 4; j++) {
            int col = n0 + wn * 64 + j * 16 + lane15;
#pragma unroll
            for (int r = 0; r < 4; r++) {
                int row = m0 + wm * 64 + i * 16 + quad * 4 + r;
                if (row < M)
                    G[(size_t)row * (H_ * C_) + h * C_ + col] = (bf16_t)acc[i][j][r];
            }
        }
}

// ---------------------------------------------------------------------------
// logits2 via MFMA: per wave one bq. A = x[bq, f(16 rows, 8 valid), c],
// B = G[bq, h(16 rows, 12 valid), c], contraction over c=768 (24 MFMAs,
// 2 interleaved acc chains). No LDS, x and G read exactly once. Grid 784.
// ---------------------------------------------------------------------------
__global__ __launch_bounds__(256) void l2_mfma(
    const bf16_t* __restrict__ x, const bf16_t* __restrict__ G,
    float* __restrict__ l2out)
{
    const int t = threadIdx.x;
    const int lane = t & 63, w = t >> 6;
    const int lane15 = lane & 15, quad = lane >> 4;
    const int bq = blockIdx.x * 4 + w;
    const int fr = lane15 < F_ ? lane15 : F_ - 1;
    const int hr = lane15 < H_ ? lane15 : H_ - 1;
    const bf16_t* xa = x + ((size_t)bq * F_ + fr) * C_ + quad * 8;
    const bf16_t* gb = G + ((size_t)bq * H_ + hr) * C_ + quad * 8;

    f32x4 acc0 = (f32x4){0.f, 0.f, 0.f, 0.f};
    f32x4 acc1 = (f32x4){0.f, 0.f, 0.f, 0.f};
#pragma unroll 4
    for (int c = 0; c < C_; c += 64) {
        bf16x8 a0 = *(const bf16x8*)(xa + c);
        bf16x8 b0 = *(const bf16x8*)(gb + c);
        bf16x8 a1 = *(const bf16x8*)(xa + c + 32);
        bf16x8 b1 = *(const bf16x8*)(gb + c + 32);
        acc0 = __builtin_amdgcn_mfma_f32_16x16x32_bf16(a0, b0, acc0, 0, 0, 0);
        acc1 = __builtin_amdgcn_mfma_f32_16x16x32_bf16(a1, b1, acc1, 0, 0, 0);
    }
    // D[row = f = quad*4+r][col = h = lane15]
#pragma unroll
    for (int r = 0; r < 4; r++) {
        int ff = quad * 4 + r;
        if (ff < F_ && lane15 < H_)
            l2out[(size_t)bq * 96 + lane15 * 8 + ff] = SCALE * (acc0[r] + acc1[r]);
    }
}

// ---------------------------------------------------------------------------
// Fused stage-1 attention, 4-wave blocks (QBLK=64) for 2 blocks/CU:
//   V global->regs (entry), QK^T -> out1, softmax, V regs->LDS + P->LDS,
//   one barrier, PV, fused xsum. Grid (F=8, 25, 24), 256 threads.
// LDS: Vt 29,696 + Ps 29,696 = 59,392 B -> 2 blocks/CU (8 waves/CU).
// ---------------------------------------------------------------------------
__global__ __launch_bounds__(256, 2) void attn1_fused(
    const bf16_t* __restrict__ qb, const bf16_t* __restrict__ kvb,
    float* __restrict__ out1, bf16_t* __restrict__ x, float* __restrict__ xsum)
{
    __shared__ bf16_t Vt[64 * 232];          // V transposed: [d][s], s padded to 224
    __shared__ bf16_t Ps[4 * 16 * 232];      // per-wave P tile [16 q][s padded]
    const int f = blockIdx.x, qt = blockIdx.y, z = blockIdx.z;
    const int b = z / H_, h = z - b * H_;
    const int t = threadIdx.x;
    const int lane = t & 63, w = t >> 6;     // wave 0..3
    const int lane15 = lane & 15, quad = lane >> 4;

    const size_t kvBase = ((size_t)b * N_ + (size_t)f * S_) * C2_;

    // ---- (1) issue V loads to registers (consumed after softmax) ----
    bf16x8 vreg[7];
#pragma unroll
    for (int i = 0; i < 7; i++) {
        int e = t + 256 * i;                 // 0..1791; valid < 1568
        int dg = e / S_, s = e - dg * S_;
        if (e >= 8 * S_) { dg = 0; s = 0; }  // safe dup address
        vreg[i] = *(const bf16x8*)(kvb + kvBase + (size_t)s * C2_ + C_ + h * D_ + dg * 8);
    }

    // ---- (2) Q A-frags (rows clamped at tail tile) ----
    const int qrow = qt * 64 + w * 16 + lane15;
    const int qrc = qrow < Q_ ? qrow : Q_ - 1;
    const bf16_t* qp = qb + ((size_t)b * Q_ + qrc) * C_ + h * D_ + quad * 8;
    bf16x8 qa0 = *(const bf16x8*)(qp);
    bf16x8 qa1 = *(const bf16x8*)(qp + 32);

    // ---- (3) zero V pad cols s in [196,224) + own-wave P pad [208,224) ----
#pragma unroll
    for (int i = 0; i < 7; i++) {
        int e = t + 256 * i;                 // 0..1791 = 64*28
        if (e < 64 * 28) {
            int dd = e / 28;
            int s  = S_ + (e - dd * 28);
            Vt[dd * 232 + s] = (bf16_t)0.f;
        }
    }
    bf16_t* Pw = Ps + w * (16 * 232);
    {
        int prow = lane >> 2, c0 = 208 + (lane & 3) * 4;
        *(bf16x4*)(Pw + prow * 232 + c0) =
            (bf16x4){(bf16_t)0.f, (bf16_t)0.f, (bf16_t)0.f, (bf16_t)0.f};
    }

    // ---- (4) QK^T: 13 n-tiles of 16 keys, K frags from global (L2-hot) ----
    f32x4 acc[13];
#pragma unroll
    for (int n = 0; n < 13; n++) acc[n] = (f32x4){0.f, 0.f, 0.f, 0.f};
#pragma unroll
    for (int n = 0; n < 13; n++) {
        int srow = n * 16 + lane15; if (srow > S_ - 1) srow = S_ - 1;  // clamp pad rows
        const bf16_t* kp = kvb + kvBase + (size_t)srow * C2_ + h * D_ + quad * 8;
        bf16x8 kb0 = *(const bf16x8*)(kp);
        bf16x8 kb1 = *(const bf16x8*)(kp + 32);
        acc[n] = __builtin_amdgcn_mfma_f32_16x16x32_bf16(qa0, kb0, acc[n], 0, 0, 0);
        acc[n] = __builtin_amdgcn_mfma_f32_16x16x32_bf16(qa1, kb1, acc[n], 0, 0, 0);
    }

    // acc[n][r] = S[q = w*16 + quad*4 + r][s = n*16 + lane15]
    // ---- scale, write logits (output 1) with row+col guards, mask pad ----
    const int qbase = qt * 64 + w * 16 + quad * 4;
    const size_t o1base = ((size_t)z * Q_ + qbase) * N_ + (size_t)f * S_;
#pragma unroll
    for (int n = 0; n < 13; n++) {
        int s = n * 16 + lane15;
        bool valid = s < S_;
#pragma unroll
        for (int r = 0; r < 4; r++) {
            float v = SCALE * acc[n][r];
            if (valid && (qbase + r) < Q_) out1[o1base + (size_t)r * N_ + s] = v;
            acc[n][r] = valid ? v : -3e38f;
        }
    }

    // ---- softmax over s: reduce across lane15 (16-lane groups) ----
    float m[4], inv[4];
#pragma unroll
    for (int r = 0; r < 4; r++) {
        float mm = acc[0][r];
#pragma unroll
        for (int n = 1; n < 13; n++) mm = fmaxf(mm, acc[n][r]);
        mm = fmaxf(mm, __shfl_xor(mm, 1));
        mm = fmaxf(mm, __shfl_xor(mm, 2));
        mm = fmaxf(mm, __shfl_xor(mm, 4));
        mm = fmaxf(mm, __shfl_xor(mm, 8));
        m[r] = mm;
    }
#pragma unroll
    for (int r = 0; r < 4; r++) {
        float ss = 0.f;
#pragma unroll
        for (int n = 0; n < 13; n++) {
            float e = __expf(acc[n][r] - m[r]);   // masked -> exp(-huge) = 0
            acc[n][r] = e;
            ss += e;
        }
        ss += __shfl_xor(ss, 1);
        ss += __shfl_xor(ss, 2);
        ss += __shfl_xor(ss, 4);
        ss += __shfl_xor(ss, 8);
        inv[r] = 1.f / ss;
    }

    // ---- (5) late V write: regs -> Vt (HBM latency hidden under QK^T) ----
#pragma unroll
    for (int i = 0; i < 7; i++) {
        int e = t + 256 * i;
        if (e < 8 * S_) {
            int dg = e / S_, s = e - dg * S_;
#pragma unroll
            for (int j = 0; j < 8; j++)
                Vt[(dg * 8 + j) * 232 + s] = vreg[i][j];
        }
    }

    // ---- (6) write normalized P (bf16) to own-wave LDS tile ----
#pragma unroll
    for (int n = 0; n < 13; n++)
#pragma unroll
        for (int r = 0; r < 4; r++)
            Pw[(quad * 4 + r) * 232 + n * 16 + lane15] = (bf16_t)(acc[n][r] * inv[r]);

    __syncthreads();                         // single barrier: Vt + Ps ready

    // ---- (7) PV: x[16 q][64 d] = P[16][224] @ V[224][64], 7 k-chunks ----
    bf16x8 pa[7];
#pragma unroll
    for (int ks = 0; ks < 7; ks++)
        pa[ks] = *(const bf16x8*)(Pw + lane15 * 232 + ks * 32 + quad * 8);

    f32x4 o[4];
#pragma unroll
    for (int nt = 0; nt < 4; nt++) o[nt] = (f32x4){0.f, 0.f, 0.f, 0.f};
#pragma unroll
    for (int nt = 0; nt < 4; nt++)
#pragma unroll
        for (int ks = 0; ks < 7; ks++) {
            bf16x8 vb = *(const bf16x8*)(Vt + (nt * 16 + lane15) * 232 + ks * 32 + quad * 8);
            o[nt] = __builtin_amdgcn_mfma_f32_16x16x32_bf16(pa[ks], vb, o[nt], 0, 0, 0);
        }

    // o[nt][r]: row q = qbase + r, col d = nt*16 + lane15
#pragma unroll
    for (int nt = 0; nt < 4; nt++)
#pragma unroll
        for (int r = 0; r < 4; r++)
            if (qbase + r < Q_)
                x[(((size_t)(b * Q_ + qbase + r)) * F_ + f) * C_ + h * D_ + nt * 16 + lane15] =
                    (bf16_t)o[nt][r];

    // ---- fused xsum: masked block sum over valid q rows, 64 atomics ----
    float part[4];
#pragma unroll
    for (int nt = 0; nt < 4; nt++) {
        part[nt] = 0.f;
#pragma unroll
        for (int r = 0; r < 4; r++)
            if (qbase + r < Q_) part[nt] += o[nt][r];
    }
    __syncthreads();                       // Vt/Ps dead in all waves
    float* red = (float*)Vt;               // reuse LDS
    if (t < 64) red[t] = 0.f;
    __syncthreads();
#pragma unroll
    for (int nt = 0; nt < 4; nt++)
        atomicAdd(&red[nt * 16 + lane15], part[nt]);
    __syncthreads();
    if (t < 64)
        atomicAdd(&xsum[((size_t)(b * F_ + f)) * C_ + h * D_ + t], red[t]);
}

// ---------------------------------------------------------------------------
// vsum[b,f,c2] = sum_c xsum[b,f,c] * Wpkv[c, 768+c2]. Grid (16, 3).
// ---------------------------------------------------------------------------
__global__ __launch_bounds__(256) void vsum_kernel(
    const float* __restrict__ xsum, const float* __restrict__ Wpkv,
    float* __restrict__ vsum)
{
    __shared__ float xs[C_];
    const int bf = blockIdx.x;
    const int t = threadIdx.x;
    for (int i = 0; i < 3; i++) xs[t + 256 * i] = xsum[(size_t)bf * C_ + t + 256 * i];
    __syncthreads();
    const int c2 = blockIdx.y * 256 + t;
    float acc = 0.f;
#pragma unroll 8
    for (int c = 0; c < C_; c++) acc += xs[c] * Wpkv[(size_t)c * C2_ + C_ + c2];
    vsum[(size_t)bf * C_ + c2] = acc;
}

// ---------------------------------------------------------------------------
// Stage-2: softmax over f (logits from l2_mfma), then
// qout[b,q,c] = sum_f p2 * vsum. Out bf16. Grid 3136 blocks.
// ---------------------------------------------------------------------------
__global__ __launch_bounds__(256) void attn2_qout(
    const float* __restrict__ logits2, const float* __restrict__ vsum,
    bf16_t* __restrict__ qout)
{
    __shared__ float p2s[96];
    const int bq = blockIdx.x;
    const int t = threadIdx.x;

    if (t < 96) {                           // t = h*8 + f
        float l = logits2[(size_t)bq * 96 + t];
        float mm = l;
        mm = fmaxf(mm, __shfl_xor(mm, 1));
        mm = fmaxf(mm, __shfl_xor(mm, 2));
        mm = fmaxf(mm, __shfl_xor(mm, 4));  // 8-lane group (same h) max
        float e = __expf(l - mm);
        float ss = e;
        ss += __shfl_xor(ss, 1);
        ss += __shfl_xor(ss, 2);
        ss += __shfl_xor(ss, 4);
        p2s[t] = e / ss;
    }
    __syncthreads();

    const int b = bq / Q_;
    for (int i = 0; i < 3; i++) {
        int c = t + 256 * i;
        int h = c >> 6;
        float acc = 0.f;
#pragma unroll
        for (int fr = 0; fr < F_; fr++)
            acc += p2s[h * 8 + fr] * vsum[((size_t)(b * F_ + fr)) * C_ + c];
        qout[(size_t)bq * C_ + c] = (bf16_t)acc;
    }
}

// ---------------------------------------------------------------------------
extern "C" void kernel_launch(void* const* d_in, const int* in_sizes, int n_in,
                              void* d_out, int out_size, void* d_ws, size_t ws_size,
                              hipStream_t stream) {
    const float* query  = (const float*)d_in[0];
    const float* memory = (const float*)d_in[1];
    const float* Wq     = (const float*)d_in[2];
    const float* Wkv    = (const float*)d_in[3];
    const float* Wpq    = (const float*)d_in[4];
    const float* Wpkv   = (const float*)d_in[5];
    const float* Wproj  = (const float*)d_in[6];
    const float* bproj  = (const float*)d_in[7];

    float* out0 = (float*)d_out;                              // [B,Q,C]
    float* out1 = (float*)d_out + (size_t)B_ * Q_ * C_;       // [B*H,Q,F,S]

    char* w = (char*)d_ws;                       // byte offsets, all 16B aligned
    bf16_t* kv_bf = (bf16_t*)(w + 0);            //   9,633,792  [B*N, 2C]
    bf16_t* q_bf  = (bf16_t*)(w + 9633792);      //   4,816,896  [B*Q, C]
    bf16_t* q2b   = (bf16_t*)(w + 14450688);     //   4,816,896  [B*Q, C]
    bf16_t* qry_b = (bf16_t*)(w + 19267584);     //   4,816,896
    bf16_t* mem_b = (bf16_t*)(w + 24084480);     //   4,816,896
    bf16_t* qo_bf = (bf16_t*)(w + 28901376);     //   4,816,896
    bf16_t* x_bf  = (bf16_t*)(w + 33718272);     //  38,535,168  [B*Q*F, C]
    bf16_t* G_bf  = (bf16_t*)(w + 72253440);     //  57,802,752  [B*Q, H, C]
    float*  lgt2  = (float*) (w + 130056192);    //   1,204,224  [B*Q, H, F]
    bf16_t* Wqt   = (bf16_t*)(w + 131260416);    //   1,179,648
    bf16_t* Wkvt  = (bf16_t*)(w + 132440064);    //   2,359,296
    bf16_t* Wpqt  = (bf16_t*)(w + 134799360);    //   1,179,648
    bf16_t* Wprjt = (bf16_t*)(w + 135979008);    //   1,179,648
    bf16_t* Wpkvb = (bf16_t*)(w + 137158656);    //   2,359,296  [C, 2C] row-major
    float*  xsum  = (float*) (w + 139517952);    //      49,152
    float*  vsum  = (float*) (w + 139567104);    //      49,152

    const int MQ = B_ * Q_;        // 3136

    // merged input conversions (query, memory, Wpkv->bf16 row-major)
    cvt3<<<5856, 256, 0, stream>>>(query, memory, Wpkv, qry_b, mem_b, Wpkvb);
    // merged weight transposes (Wq, Wkv, Wpq, Wproj)
    transpose4<<<dim3(48, 24, 4), 256, 0, stream>>>(Wq, Wkv, Wpq, Wproj,
                                                    Wqt, Wkvt, Wpqt, Wprjt);

    // q = query @ Wq, kv = memory @ Wkv — single merged launch (450 blocks)
    gemm_qkv<<<dim3(18, 25), 256, 0, stream>>>(qry_b, Wqt, q_bf, mem_b, Wkvt, kv_bf);
    // q2 = q @ Wpq (bf16)
    gemm_mfma<<<dim3(6, 25), 256, 0, stream>>>(q_bf, Wpqt, nullptr, q2b, MQ, C_, C_, nullptr);
    // fused stage-1: logits (output 1) + softmax + PV -> x (bf16) + xsum
    hipMemsetAsync(xsum, 0, (size_t)B_ * F_ * C_ * sizeof(float), stream);
    attn1_fused<<<dim3(F_, 25, B_ * H_), 256, 0, stream>>>(q_bf, kv_bf, out1, x_bf, xsum);
    // G[bq,h,:] = Wpkv_k-head-slice @ q2-head-slice
    gemm_g<<<dim3(6, 25, H_), 256, 0, stream>>>(q2b, Wpkvb, G_bf, MQ);
    // logits2 = SCALE * x . G  (MFMA, x/G read exactly once)
    l2_mfma<<<MQ / 4, 256, 0, stream>>>(x_bf, G_bf, lgt2);
    // vsum = xsum @ Wpkv[:, 768:]
    vsum_kernel<<<dim3(16, 3), 256, 0, stream>>>(xsum, Wpkv, vsum);
    // stage-2 attention -> qout (bf16, pre-projection)
    attn2_qout<<<MQ, 256, 0, stream>>>(lgt2, vsum, qo_bf);
    // out0 = qout @ Wproj + bproj
    gemm_mfma<<<dim3(6, 25), 256, 0, stream>>>(qo_bf, Wprjt, out0, nullptr, MQ, C_, C_, bproj);
}